// Round 9
// baseline (344.404 us; speedup 1.0000x reference)
//
#include <hip/hip_runtime.h>

#define CH 64
#define BNODES 128           // nodes per bucket (dst >> 7)
#define NB_MAX 1024
#define CUR_PAD 16           // cursor padding: 16 ints = 64 B = own cache line
#define SCAT_CHUNK 2048      // edges per scatter block (782 blocks -> ~3/CU)
#define BSLACK 1024          // per-bucket padding slack (>= 7*BNODES + align)

typedef unsigned short ushort_t;
typedef unsigned int uint_t;
typedef short short8_t __attribute__((ext_vector_type(8)));
typedef float float4_t __attribute__((ext_vector_type(4)));

static __device__ __forceinline__ ushort_t f2bf(float x) {
    uint_t u = __float_as_uint(x);
    u = (u + 0x7FFFu + ((u >> 16) & 1u)) >> 16;   // RNE
    return (ushort_t)u;
}
static __device__ __forceinline__ float bf2f(ushort_t s) {
    return __uint_as_float((uint_t)s << 16);
}

// ---------------- W transpose+convert: Wt[n][k] = bf16(W[k][n]), n<64 ----------------
__global__ __launch_bounds__(256) void wt_kernel(
    const float* __restrict__ W, ushort_t* __restrict__ Wt, int K)
{
    for (int i = threadIdx.x; i < K * CH; i += 256) {
        int n = i / K, k = i % K;
        Wt[i] = f2bf(W[(size_t)k * CH + n]);
    }
}

// ---------------- MFMA GEMM: outb[r][64] = bf16( h[r][K] @ W[K][64] ), + zero row at r==n ----
template<int K, typename T>
__global__ __launch_bounds__(256) void gemm_mfma(
    const T* __restrict__ h, const ushort_t* __restrict__ Wt,
    ushort_t* __restrict__ outb, int n)
{
    constexpr int LDH = K + 8;
    constexpr int C8  = K / 8;
    constexpr int KC  = K / 32;
    __shared__ ushort_t Hs[128 * LDH];

    const int t    = threadIdx.x;
    const int lane = t & 63;
    const int wv   = t >> 6;
    const int l15  = lane & 15;
    const int quad = lane >> 4;
    const int row0 = blockIdx.x * 128;

    short8_t bfrag[4][KC];
    #pragma unroll
    for (int nt = 0; nt < 4; ++nt)
        #pragma unroll
        for (int kc = 0; kc < KC; ++kc)
            bfrag[nt][kc] = *(const short8_t*)(Wt + (size_t)(nt * 16 + l15) * K + kc * 32 + quad * 8);

    for (int idx = t; idx < 128 * C8; idx += 256) {
        int r  = idx / C8;
        int c8 = idx % C8;
        int rg = row0 + r;
        short8_t v = (short8_t)0;
        if (rg < n) {
            if constexpr (sizeof(T) == 4) {
                const float* p = (const float*)h + (size_t)rg * K + c8 * 8;
                float4 f0 = *(const float4*)p;
                float4 f1 = *(const float4*)(p + 4);
                v[0] = (short)f2bf(f0.x); v[1] = (short)f2bf(f0.y);
                v[2] = (short)f2bf(f0.z); v[3] = (short)f2bf(f0.w);
                v[4] = (short)f2bf(f1.x); v[5] = (short)f2bf(f1.y);
                v[6] = (short)f2bf(f1.z); v[7] = (short)f2bf(f1.w);
            } else {
                v = *(const short8_t*)((const ushort_t*)h + (size_t)rg * K + c8 * 8);
            }
        }
        *(short8_t*)&Hs[r * LDH + c8 * 8] = v;
    }
    __syncthreads();

    float4_t acc[2][4];
    #pragma unroll
    for (int mi = 0; mi < 2; ++mi)
        #pragma unroll
        for (int nt = 0; nt < 4; ++nt)
            acc[mi][nt] = (float4_t)0.f;

    #pragma unroll
    for (int kc = 0; kc < KC; ++kc) {
        short8_t a0 = *(const short8_t*)&Hs[(wv * 32 +      l15) * LDH + kc * 32 + quad * 8];
        short8_t a1 = *(const short8_t*)&Hs[(wv * 32 + 16 + l15) * LDH + kc * 32 + quad * 8];
        #pragma unroll
        for (int nt = 0; nt < 4; ++nt) {
            acc[0][nt] = __builtin_amdgcn_mfma_f32_16x16x32_bf16(a0, bfrag[nt][kc], acc[0][nt], 0, 0, 0);
            acc[1][nt] = __builtin_amdgcn_mfma_f32_16x16x32_bf16(a1, bfrag[nt][kc], acc[1][nt], 0, 0, 0);
        }
    }

    #pragma unroll
    for (int mi = 0; mi < 2; ++mi) {
        #pragma unroll
        for (int r = 0; r < 4; ++r) {
            int row = row0 + wv * 32 + mi * 16 + quad * 4 + r;
            if (row <= n) {
                #pragma unroll
                for (int nt = 0; nt < 4; ++nt)
                    outb[(size_t)row * CH + nt * 16 + l15] = f2bf(acc[mi][nt][r]);
            }
        }
    }
}

// ---------------- bucket histogram (LDS-staged) ----------------
__global__ __launch_bounds__(256) void bucket_hist(
    const int* __restrict__ dst, int* __restrict__ bcnt, int E, int NB)
{
    __shared__ int h[NB_MAX];
    for (int i = threadIdx.x; i < NB; i += 256) h[i] = 0;
    __syncthreads();
    for (int i = blockIdx.x * 256 + threadIdx.x; i < E; i += gridDim.x * 256)
        atomicAdd(&h[dst[i] >> 7], 1);
    __syncthreads();
    for (int i = threadIdx.x; i < NB; i += 256) {
        int v = h[i];
        if (v) atomicAdd(&bcnt[i], v);
    }
}

// ---------------- single-block exclusive scan over NB (<=1024) counts ----------------
__global__ __launch_bounds__(256) void bucket_scan(
    const int* __restrict__ bcnt, int* __restrict__ boff,
    int* __restrict__ cursor, int NB)
{
    __shared__ int tsum[256];
    int t = threadIdx.x;
    int base = t * 4;
    int c[4];
    #pragma unroll
    for (int j = 0; j < 4; ++j) {
        int i = base + j;
        c[j] = (i < NB) ? bcnt[i] : 0;
    }
    int local = c[0] + c[1] + c[2] + c[3];
    tsum[t] = local;
    __syncthreads();
    for (int off = 1; off < 256; off <<= 1) {
        int v = (t >= off) ? tsum[t - off] : 0;
        __syncthreads();
        tsum[t] += v;
        __syncthreads();
    }
    int p = tsum[t] - local;
    #pragma unroll
    for (int j = 0; j < 4; ++j) {
        int i = base + j;
        if (i < NB) { boff[i] = p; cursor[i * CUR_PAD] = p; }
        p += c[j];
    }
    if (t == 255) boff[NB] = tsum[255];
}

// ---------------- block-aggregated scatter into bucket-major packed list ----------------
// packed = ((dst & 127) << 17) | src     (src < 2^17)
__global__ __launch_bounds__(256) void bucket_scatter_blk(
    const int* __restrict__ src, const int* __restrict__ dst,
    int* __restrict__ cursor, int* __restrict__ bucketed, int E, int NB)
{
    __shared__ int hist[NB_MAX];
    __shared__ int rbase[NB_MAX];
    __shared__ int lcur[NB_MAX];

    const int t = threadIdx.x;
    const int s = blockIdx.x * SCAT_CHUNK;
    const int e = min(s + SCAT_CHUNK, E);

    for (int i = t; i < NB; i += 256) hist[i] = 0;
    __syncthreads();

    for (int i = s + t; i < e; i += 256)
        atomicAdd(&hist[dst[i] >> 7], 1);
    __syncthreads();

    for (int i = t; i < NB; i += 256) {
        int c = hist[i];
        rbase[i] = c ? atomicAdd(&cursor[i * CUR_PAD], c) : 0;
        lcur[i] = 0;
    }
    __syncthreads();

    for (int i = s + t; i < e; i += 256) {
        int d = dst[i];
        int b = d >> 7;
        int p = atomicAdd(&lcur[b], 1);
        bucketed[rbase[b] + p] = ((d & 127) << 17) | src[i];
    }
}

// ---------------- per-bucket counting sort -> padded per-node CSR segments ----------------
__global__ __launch_bounds__(256) void node_sort(
    const int* __restrict__ bucketed, const int* __restrict__ boff,
    int* __restrict__ sorted_src, int2* __restrict__ seg, int N, int zrow)
{
    __shared__ int cnt[BNODES];
    __shared__ int sc[BNODES];
    __shared__ int cur[BNODES];
    const int bk = blockIdx.x;
    const int t  = threadIdx.x;
    const int s  = boff[bk];
    const int e  = boff[bk + 1];
    const int sbase = (s + bk * BSLACK + 7) & ~7;

    if (t < BNODES) cnt[t] = 0;
    __syncthreads();
    for (int i = s + t; i < e; i += 256)
        atomicAdd(&cnt[((unsigned)bucketed[i]) >> 17], 1);
    __syncthreads();

    int pc = 0;
    if (t < BNODES) { pc = (cnt[t] + 7) & ~7; sc[t] = pc; }
    __syncthreads();
    for (int o = 1; o < BNODES; o <<= 1) {
        int v = (t < BNODES && t >= o) ? sc[t - o] : 0;
        __syncthreads();
        if (t < BNODES) sc[t] += v;
        __syncthreads();
    }
    if (t < BNODES) {
        int pexcl = sc[t] - pc;
        cur[t] = pexcl;
        int node = bk * BNODES + t;
        if (node < N) seg[node] = make_int2(sbase + pexcl, pc);
        for (int k = cnt[t]; k < pc; ++k)       // pad entries -> zero row
            sorted_src[sbase + pexcl + k] = zrow;
    }
    __syncthreads();

    for (int i = s + t; i < e; i += 256) {
        int p = bucketed[i];
        int d = ((unsigned)p) >> 17;
        int pos = atomicAdd(&cur[d], 1);
        sorted_src[sbase + pos] = p & 0x1FFFF;
    }
}

// ---------------- aggregate ----------------
// out[d][c] = bias[c] + sum_{e in seg(d)} bf2f(hwb[src[e]][c])
// Segments padded to x8; indices uniform -> scalar row pointers; 16 gathers in flight.
template<bool BF16_RELU_OUT>
__global__ __launch_bounds__(256) void aggregate_kernel(
    const ushort_t* __restrict__ hwb, const int* __restrict__ sorted_src,
    const int2* __restrict__ seg, const float* __restrict__ bias,
    ushort_t* __restrict__ outb, float* __restrict__ outf, int N)
{
    const int lane = threadIdx.x & 63;
    const int node = blockIdx.x * 4 + (threadIdx.x >> 6);
    if (node >= N) return;

    int2 sc   = seg[node];
    int  base = __builtin_amdgcn_readfirstlane(sc.x);
    int  pc   = __builtin_amdgcn_readfirstlane(sc.y);

    const int4* sp4 = (const int4*)(sorted_src + base);   // base % 8 == 0 -> 16B aligned

    float a0 = bias[lane], a1 = 0.f, a2 = 0.f, a3 = 0.f;
    float a4 = 0.f, a5 = 0.f, a6 = 0.f, a7 = 0.f;

    int u = 0;
    for (; u + 16 <= pc; u += 16) {
        int4 q0 = sp4[(u >> 2) + 0];
        int4 q1 = sp4[(u >> 2) + 1];
        int4 q2 = sp4[(u >> 2) + 2];
        int4 q3 = sp4[(u >> 2) + 3];
        int i0  = __builtin_amdgcn_readfirstlane(q0.x);
        int i1  = __builtin_amdgcn_readfirstlane(q0.y);
        int i2  = __builtin_amdgcn_readfirstlane(q0.z);
        int i3  = __builtin_amdgcn_readfirstlane(q0.w);
        int i4  = __builtin_amdgcn_readfirstlane(q1.x);
        int i5  = __builtin_amdgcn_readfirstlane(q1.y);
        int i6  = __builtin_amdgcn_readfirstlane(q1.z);
        int i7  = __builtin_amdgcn_readfirstlane(q1.w);
        int i8  = __builtin_amdgcn_readfirstlane(q2.x);
        int i9  = __builtin_amdgcn_readfirstlane(q2.y);
        int i10 = __builtin_amdgcn_readfirstlane(q2.z);
        int i11 = __builtin_amdgcn_readfirstlane(q2.w);
        int i12 = __builtin_amdgcn_readfirstlane(q3.x);
        int i13 = __builtin_amdgcn_readfirstlane(q3.y);
        int i14 = __builtin_amdgcn_readfirstlane(q3.z);
        int i15 = __builtin_amdgcn_readfirstlane(q3.w);
        ushort_t v0  = hwb[(size_t)i0  * CH + lane];
        ushort_t v1  = hwb[(size_t)i1  * CH + lane];
        ushort_t v2  = hwb[(size_t)i2  * CH + lane];
        ushort_t v3  = hwb[(size_t)i3  * CH + lane];
        ushort_t v4  = hwb[(size_t)i4  * CH + lane];
        ushort_t v5  = hwb[(size_t)i5  * CH + lane];
        ushort_t v6  = hwb[(size_t)i6  * CH + lane];
        ushort_t v7  = hwb[(size_t)i7  * CH + lane];
        ushort_t v8  = hwb[(size_t)i8  * CH + lane];
        ushort_t v9  = hwb[(size_t)i9  * CH + lane];
        ushort_t v10 = hwb[(size_t)i10 * CH + lane];
        ushort_t v11 = hwb[(size_t)i11 * CH + lane];
        ushort_t v12 = hwb[(size_t)i12 * CH + lane];
        ushort_t v13 = hwb[(size_t)i13 * CH + lane];
        ushort_t v14 = hwb[(size_t)i14 * CH + lane];
        ushort_t v15 = hwb[(size_t)i15 * CH + lane];
        a0 += bf2f(v0);  a1 += bf2f(v1);  a2 += bf2f(v2);  a3 += bf2f(v3);
        a4 += bf2f(v4);  a5 += bf2f(v5);  a6 += bf2f(v6);  a7 += bf2f(v7);
        a0 += bf2f(v8);  a1 += bf2f(v9);  a2 += bf2f(v10); a3 += bf2f(v11);
        a4 += bf2f(v12); a5 += bf2f(v13); a6 += bf2f(v14); a7 += bf2f(v15);
    }
    for (; u < pc; u += 8) {
        int4 qa = sp4[(u >> 2) + 0];
        int4 qb = sp4[(u >> 2) + 1];
        int i0 = __builtin_amdgcn_readfirstlane(qa.x);
        int i1 = __builtin_amdgcn_readfirstlane(qa.y);
        int i2 = __builtin_amdgcn_readfirstlane(qa.z);
        int i3 = __builtin_amdgcn_readfirstlane(qa.w);
        int i4 = __builtin_amdgcn_readfirstlane(qb.x);
        int i5 = __builtin_amdgcn_readfirstlane(qb.y);
        int i6 = __builtin_amdgcn_readfirstlane(qb.z);
        int i7 = __builtin_amdgcn_readfirstlane(qb.w);
        ushort_t v0 = hwb[(size_t)i0 * CH + lane];
        ushort_t v1 = hwb[(size_t)i1 * CH + lane];
        ushort_t v2 = hwb[(size_t)i2 * CH + lane];
        ushort_t v3 = hwb[(size_t)i3 * CH + lane];
        ushort_t v4 = hwb[(size_t)i4 * CH + lane];
        ushort_t v5 = hwb[(size_t)i5 * CH + lane];
        ushort_t v6 = hwb[(size_t)i6 * CH + lane];
        ushort_t v7 = hwb[(size_t)i7 * CH + lane];
        a0 += bf2f(v0); a1 += bf2f(v1); a2 += bf2f(v2); a3 += bf2f(v3);
        a4 += bf2f(v4); a5 += bf2f(v5); a6 += bf2f(v6); a7 += bf2f(v7);
    }

    float r = ((a0 + a1) + (a2 + a3)) + ((a4 + a5) + (a6 + a7));
    if (BF16_RELU_OUT) {
        outb[(size_t)node * CH + lane] = f2bf(fmaxf(r, 0.f));
    } else {
        outf[(size_t)node * CH + lane] = r;
    }
}

extern "C" void kernel_launch(void* const* d_in, const int* in_sizes, int n_in,
                              void* d_out, int out_size, void* d_ws, size_t ws_size,
                              hipStream_t stream) {
    const float* x    = (const float*)d_in[0];
    const int*   esrc = (const int*)  d_in[1];
    const int*   edst = (const int*)  d_in[2];
    const float* W1   = (const float*)d_in[3];
    const float* b1   = (const float*)d_in[4];
    const float* W2   = (const float*)d_in[5];
    const float* b2   = (const float*)d_in[6];
    const float* W3   = (const float*)d_in[7];
    const float* b3   = (const float*)d_in[8];
    float* out = (float*)d_out;

    const int N  = in_sizes[0] / 128;
    const int E  = in_sizes[1];
    const int NB = (N + BNODES - 1) / BNODES;   // 782 for N=100000

    // workspace layout (~43 MB)
    char* ws = (char*)d_ws;
    ushort_t* hwb   = (ushort_t*)ws; ws += (size_t)(N + 1) * CH * 2;  // bf16 hw + zero row
    ushort_t* hb    = (ushort_t*)ws; ws += (size_t)N * CH * 2;        // bf16 relu(agg)
    int* bucketed   = (int*)ws;      ws += (size_t)E * 4;
    ws = (char*)(((uintptr_t)ws + 15) & ~(uintptr_t)15);
    int* sorted_src = (int*)ws;      ws += ((size_t)E + (size_t)NB * BSLACK + 64) * 4;
    int2* seg       = (int2*)ws;     ws += (size_t)N * 8;
    int* bcnt       = (int*)ws;      ws += (size_t)NB * 4;
    int* boff       = (int*)ws;      ws += (size_t)(NB + 1) * 4;
    ws = (char*)(((uintptr_t)ws + 63) & ~(uintptr_t)63);
    int* cursor     = (int*)ws;      ws += (size_t)NB * CUR_PAD * 4;
    ws = (char*)(((uintptr_t)ws + 15) & ~(uintptr_t)15);
    ushort_t* Wt1   = (ushort_t*)ws; ws += (size_t)CH * 128 * 2;
    ushort_t* Wt2   = (ushort_t*)ws; ws += (size_t)CH * 64 * 2;
    ushort_t* Wt3   = (ushort_t*)ws; ws += (size_t)CH * 64 * 2;

    dim3 blk(256);
    int gemmGrid = (N + 1 + 127) / 128;          // covers zero row at index N
    int aggGrid  = (N + 3) / 4;
    int scatGrid = (E + SCAT_CHUNK - 1) / SCAT_CHUNK;

    // ---- W transpose+convert (tiny) ----
    wt_kernel<<<1, blk, 0, stream>>>(W1, Wt1, 128);
    wt_kernel<<<1, blk, 0, stream>>>(W2, Wt2, 64);
    wt_kernel<<<1, blk, 0, stream>>>(W3, Wt3, 64);

    // ---- CSR build via buckets (once; shared by all 3 layers) ----
    hipMemsetAsync(bcnt, 0, (size_t)NB * 4, stream);
    bucket_hist<<<256, blk, 0, stream>>>(edst, bcnt, E, NB);
    bucket_scan<<<1, blk, 0, stream>>>(bcnt, boff, cursor, NB);
    bucket_scatter_blk<<<scatGrid, blk, 0, stream>>>(esrc, edst, cursor, bucketed, E, NB);
    node_sort<<<NB, blk, 0, stream>>>(bucketed, boff, sorted_src, seg, N, N /*zero row*/);

    // ---- layer 1 ----
    gemm_mfma<128, float><<<gemmGrid, blk, 0, stream>>>(x, Wt1, hwb, N);
    aggregate_kernel<true><<<aggGrid, blk, 0, stream>>>(hwb, sorted_src, seg, b1, hb, nullptr, N);
    // ---- layer 2 ----
    gemm_mfma<64, ushort_t><<<gemmGrid, blk, 0, stream>>>(hb, Wt2, hwb, N);
    aggregate_kernel<true><<<aggGrid, blk, 0, stream>>>(hwb, sorted_src, seg, b2, hb, nullptr, N);
    // ---- layer 3 ----
    gemm_mfma<64, ushort_t><<<gemmGrid, blk, 0, stream>>>(hb, Wt3, hwb, N);
    aggregate_kernel<false><<<aggGrid, blk, 0, stream>>>(hwb, sorted_src, seg, b3, nullptr, out, N);
}

// Round 10
// 306.273 us; speedup vs baseline: 1.1245x; 1.1245x over previous
//
#include <hip/hip_runtime.h>

#define CH 64
#define BNODES 128           // nodes per bucket (dst >> 7)
#define NB_MAX 1024
#define CUR_PAD 16           // cursor padding: 16 ints = 64 B = own cache line
#define SCAT_CHUNK 8192      // edges per scatter block (long runs -> full-line writes)
#define SCAT_THREADS 1024    // 16 waves/block -> 4 waves/SIMD latency hiding
#define BSLACK 1024          // per-bucket padding slack (>= 7*BNODES + align)

typedef unsigned short ushort_t;
typedef unsigned int uint_t;
typedef short short8_t __attribute__((ext_vector_type(8)));
typedef float float4_t __attribute__((ext_vector_type(4)));

static __device__ __forceinline__ ushort_t f2bf(float x) {
    uint_t u = __float_as_uint(x);
    u = (u + 0x7FFFu + ((u >> 16) & 1u)) >> 16;   // RNE
    return (ushort_t)u;
}
static __device__ __forceinline__ float bf2f(ushort_t s) {
    return __uint_as_float((uint_t)s << 16);
}

// ---------------- W transpose+convert: Wt[n][k] = bf16(W[k][n]), n<64 ----------------
__global__ __launch_bounds__(256) void wt_kernel(
    const float* __restrict__ W, ushort_t* __restrict__ Wt, int K)
{
    for (int i = threadIdx.x; i < K * CH; i += 256) {
        int n = i / K, k = i % K;
        Wt[i] = f2bf(W[(size_t)k * CH + n]);
    }
}

// ---------------- MFMA GEMM: outb[r][64] = bf16( h[r][K] @ W[K][64] ), + zero row at r==n ----
template<int K, typename T>
__global__ __launch_bounds__(256) void gemm_mfma(
    const T* __restrict__ h, const ushort_t* __restrict__ Wt,
    ushort_t* __restrict__ outb, int n)
{
    constexpr int LDH = K + 8;
    constexpr int C8  = K / 8;
    constexpr int KC  = K / 32;
    __shared__ ushort_t Hs[128 * LDH];

    const int t    = threadIdx.x;
    const int lane = t & 63;
    const int wv   = t >> 6;
    const int l15  = lane & 15;
    const int quad = lane >> 4;
    const int row0 = blockIdx.x * 128;

    short8_t bfrag[4][KC];
    #pragma unroll
    for (int nt = 0; nt < 4; ++nt)
        #pragma unroll
        for (int kc = 0; kc < KC; ++kc)
            bfrag[nt][kc] = *(const short8_t*)(Wt + (size_t)(nt * 16 + l15) * K + kc * 32 + quad * 8);

    for (int idx = t; idx < 128 * C8; idx += 256) {
        int r  = idx / C8;
        int c8 = idx % C8;
        int rg = row0 + r;
        short8_t v = (short8_t)0;
        if (rg < n) {
            if constexpr (sizeof(T) == 4) {
                const float* p = (const float*)h + (size_t)rg * K + c8 * 8;
                float4 f0 = *(const float4*)p;
                float4 f1 = *(const float4*)(p + 4);
                v[0] = (short)f2bf(f0.x); v[1] = (short)f2bf(f0.y);
                v[2] = (short)f2bf(f0.z); v[3] = (short)f2bf(f0.w);
                v[4] = (short)f2bf(f1.x); v[5] = (short)f2bf(f1.y);
                v[6] = (short)f2bf(f1.z); v[7] = (short)f2bf(f1.w);
            } else {
                v = *(const short8_t*)((const ushort_t*)h + (size_t)rg * K + c8 * 8);
            }
        }
        *(short8_t*)&Hs[r * LDH + c8 * 8] = v;
    }
    __syncthreads();

    float4_t acc[2][4];
    #pragma unroll
    for (int mi = 0; mi < 2; ++mi)
        #pragma unroll
        for (int nt = 0; nt < 4; ++nt)
            acc[mi][nt] = (float4_t)0.f;

    #pragma unroll
    for (int kc = 0; kc < KC; ++kc) {
        short8_t a0 = *(const short8_t*)&Hs[(wv * 32 +      l15) * LDH + kc * 32 + quad * 8];
        short8_t a1 = *(const short8_t*)&Hs[(wv * 32 + 16 + l15) * LDH + kc * 32 + quad * 8];
        #pragma unroll
        for (int nt = 0; nt < 4; ++nt) {
            acc[0][nt] = __builtin_amdgcn_mfma_f32_16x16x32_bf16(a0, bfrag[nt][kc], acc[0][nt], 0, 0, 0);
            acc[1][nt] = __builtin_amdgcn_mfma_f32_16x16x32_bf16(a1, bfrag[nt][kc], acc[1][nt], 0, 0, 0);
        }
    }

    #pragma unroll
    for (int mi = 0; mi < 2; ++mi) {
        #pragma unroll
        for (int r = 0; r < 4; ++r) {
            int row = row0 + wv * 32 + mi * 16 + quad * 4 + r;
            if (row <= n) {
                #pragma unroll
                for (int nt = 0; nt < 4; ++nt)
                    outb[(size_t)row * CH + nt * 16 + l15] = f2bf(acc[mi][nt][r]);
            }
        }
    }
}

// ---------------- bucket histogram (LDS-staged) ----------------
__global__ __launch_bounds__(256) void bucket_hist(
    const int* __restrict__ dst, int* __restrict__ bcnt, int E, int NB)
{
    __shared__ int h[NB_MAX];
    for (int i = threadIdx.x; i < NB; i += 256) h[i] = 0;
    __syncthreads();
    for (int i = blockIdx.x * 256 + threadIdx.x; i < E; i += gridDim.x * 256)
        atomicAdd(&h[dst[i] >> 7], 1);
    __syncthreads();
    for (int i = threadIdx.x; i < NB; i += 256) {
        int v = h[i];
        if (v) atomicAdd(&bcnt[i], v);
    }
}

// ---------------- single-block exclusive scan over NB (<=1024) counts ----------------
__global__ __launch_bounds__(256) void bucket_scan(
    const int* __restrict__ bcnt, int* __restrict__ boff,
    int* __restrict__ cursor, int NB)
{
    __shared__ int tsum[256];
    int t = threadIdx.x;
    int base = t * 4;
    int c[4];
    #pragma unroll
    for (int j = 0; j < 4; ++j) {
        int i = base + j;
        c[j] = (i < NB) ? bcnt[i] : 0;
    }
    int local = c[0] + c[1] + c[2] + c[3];
    tsum[t] = local;
    __syncthreads();
    for (int off = 1; off < 256; off <<= 1) {
        int v = (t >= off) ? tsum[t - off] : 0;
        __syncthreads();
        tsum[t] += v;
        __syncthreads();
    }
    int p = tsum[t] - local;
    #pragma unroll
    for (int j = 0; j < 4; ++j) {
        int i = base + j;
        if (i < NB) { boff[i] = p; cursor[i * CUR_PAD] = p; }
        p += c[j];
    }
    if (t == 255) boff[NB] = tsum[255];
}

// ---------------- block-aggregated scatter into bucket-major packed list ----------------
// packed = ((dst & 127) << 17) | src     (src < 2^17)
__global__ __launch_bounds__(SCAT_THREADS) void bucket_scatter_blk(
    const int* __restrict__ src, const int* __restrict__ dst,
    int* __restrict__ cursor, int* __restrict__ bucketed, int E, int NB)
{
    __shared__ int hist[NB_MAX];
    __shared__ int rbase[NB_MAX];
    __shared__ int lcur[NB_MAX];

    const int t = threadIdx.x;
    const int s = blockIdx.x * SCAT_CHUNK;
    const int e = min(s + SCAT_CHUNK, E);

    for (int i = t; i < NB; i += SCAT_THREADS) hist[i] = 0;
    __syncthreads();

    for (int i = s + t; i < e; i += SCAT_THREADS)
        atomicAdd(&hist[dst[i] >> 7], 1);
    __syncthreads();

    for (int i = t; i < NB; i += SCAT_THREADS) {
        int c = hist[i];
        rbase[i] = c ? atomicAdd(&cursor[i * CUR_PAD], c) : 0;
        lcur[i] = 0;
    }
    __syncthreads();

    for (int i = s + t; i < e; i += SCAT_THREADS) {
        int d = dst[i];
        int b = d >> 7;
        int p = atomicAdd(&lcur[b], 1);
        bucketed[rbase[b] + p] = ((d & 127) << 17) | src[i];
    }
}

// ---------------- per-bucket counting sort -> padded per-node CSR segments ----------------
__global__ __launch_bounds__(256) void node_sort(
    const int* __restrict__ bucketed, const int* __restrict__ boff,
    int* __restrict__ sorted_src, int2* __restrict__ seg, int N, int zrow)
{
    __shared__ int cnt[BNODES];
    __shared__ int sc[BNODES];
    __shared__ int cur[BNODES];
    const int bk = blockIdx.x;
    const int t  = threadIdx.x;
    const int s  = boff[bk];
    const int e  = boff[bk + 1];
    const int sbase = (s + bk * BSLACK + 7) & ~7;

    if (t < BNODES) cnt[t] = 0;
    __syncthreads();
    for (int i = s + t; i < e; i += 256)
        atomicAdd(&cnt[((unsigned)bucketed[i]) >> 17], 1);
    __syncthreads();

    int pc = 0;
    if (t < BNODES) { pc = (cnt[t] + 7) & ~7; sc[t] = pc; }
    __syncthreads();
    for (int o = 1; o < BNODES; o <<= 1) {
        int v = (t < BNODES && t >= o) ? sc[t - o] : 0;
        __syncthreads();
        if (t < BNODES) sc[t] += v;
        __syncthreads();
    }
    if (t < BNODES) {
        int pexcl = sc[t] - pc;
        cur[t] = pexcl;
        int node = bk * BNODES + t;
        if (node < N) seg[node] = make_int2(sbase + pexcl, pc);
        for (int k = cnt[t]; k < pc; ++k)       // pad entries -> zero row
            sorted_src[sbase + pexcl + k] = zrow;
    }
    __syncthreads();

    for (int i = s + t; i < e; i += 256) {
        int p = bucketed[i];
        int d = ((unsigned)p) >> 17;
        int pos = atomicAdd(&cur[d], 1);
        sorted_src[sbase + pos] = p & 0x1FFFF;
    }
}

// ---------------- aggregate ----------------
// out[d][c] = bias[c] + sum_{e in seg(d)} bf2f(hwb[src[e]][c])
template<bool BF16_RELU_OUT>
__global__ __launch_bounds__(256) void aggregate_kernel(
    const ushort_t* __restrict__ hwb, const int* __restrict__ sorted_src,
    const int2* __restrict__ seg, const float* __restrict__ bias,
    ushort_t* __restrict__ outb, float* __restrict__ outf, int N)
{
    const int lane = threadIdx.x & 63;
    const int node = blockIdx.x * 4 + (threadIdx.x >> 6);
    if (node >= N) return;

    int2 sc   = seg[node];
    int  base = __builtin_amdgcn_readfirstlane(sc.x);
    int  pc   = __builtin_amdgcn_readfirstlane(sc.y);

    const int4* sp4 = (const int4*)(sorted_src + base);   // base % 8 == 0 -> 16B aligned

    float a0 = bias[lane], a1 = 0.f, a2 = 0.f, a3 = 0.f;
    float a4 = 0.f, a5 = 0.f, a6 = 0.f, a7 = 0.f;

    int u = 0;
    for (; u + 16 <= pc; u += 16) {
        int4 q0 = sp4[(u >> 2) + 0];
        int4 q1 = sp4[(u >> 2) + 1];
        int4 q2 = sp4[(u >> 2) + 2];
        int4 q3 = sp4[(u >> 2) + 3];
        int i0  = __builtin_amdgcn_readfirstlane(q0.x);
        int i1  = __builtin_amdgcn_readfirstlane(q0.y);
        int i2  = __builtin_amdgcn_readfirstlane(q0.z);
        int i3  = __builtin_amdgcn_readfirstlane(q0.w);
        int i4  = __builtin_amdgcn_readfirstlane(q1.x);
        int i5  = __builtin_amdgcn_readfirstlane(q1.y);
        int i6  = __builtin_amdgcn_readfirstlane(q1.z);
        int i7  = __builtin_amdgcn_readfirstlane(q1.w);
        int i8  = __builtin_amdgcn_readfirstlane(q2.x);
        int i9  = __builtin_amdgcn_readfirstlane(q2.y);
        int i10 = __builtin_amdgcn_readfirstlane(q2.z);
        int i11 = __builtin_amdgcn_readfirstlane(q2.w);
        int i12 = __builtin_amdgcn_readfirstlane(q3.x);
        int i13 = __builtin_amdgcn_readfirstlane(q3.y);
        int i14 = __builtin_amdgcn_readfirstlane(q3.z);
        int i15 = __builtin_amdgcn_readfirstlane(q3.w);
        ushort_t v0  = hwb[(size_t)i0  * CH + lane];
        ushort_t v1  = hwb[(size_t)i1  * CH + lane];
        ushort_t v2  = hwb[(size_t)i2  * CH + lane];
        ushort_t v3  = hwb[(size_t)i3  * CH + lane];
        ushort_t v4  = hwb[(size_t)i4  * CH + lane];
        ushort_t v5  = hwb[(size_t)i5  * CH + lane];
        ushort_t v6  = hwb[(size_t)i6  * CH + lane];
        ushort_t v7  = hwb[(size_t)i7  * CH + lane];
        ushort_t v8  = hwb[(size_t)i8  * CH + lane];
        ushort_t v9  = hwb[(size_t)i9  * CH + lane];
        ushort_t v10 = hwb[(size_t)i10 * CH + lane];
        ushort_t v11 = hwb[(size_t)i11 * CH + lane];
        ushort_t v12 = hwb[(size_t)i12 * CH + lane];
        ushort_t v13 = hwb[(size_t)i13 * CH + lane];
        ushort_t v14 = hwb[(size_t)i14 * CH + lane];
        ushort_t v15 = hwb[(size_t)i15 * CH + lane];
        a0 += bf2f(v0);  a1 += bf2f(v1);  a2 += bf2f(v2);  a3 += bf2f(v3);
        a4 += bf2f(v4);  a5 += bf2f(v5);  a6 += bf2f(v6);  a7 += bf2f(v7);
        a0 += bf2f(v8);  a1 += bf2f(v9);  a2 += bf2f(v10); a3 += bf2f(v11);
        a4 += bf2f(v12); a5 += bf2f(v13); a6 += bf2f(v14); a7 += bf2f(v15);
    }
    for (; u < pc; u += 8) {
        int4 qa = sp4[(u >> 2) + 0];
        int4 qb = sp4[(u >> 2) + 1];
        int i0 = __builtin_amdgcn_readfirstlane(qa.x);
        int i1 = __builtin_amdgcn_readfirstlane(qa.y);
        int i2 = __builtin_amdgcn_readfirstlane(qa.z);
        int i3 = __builtin_amdgcn_readfirstlane(qa.w);
        int i4 = __builtin_amdgcn_readfirstlane(qb.x);
        int i5 = __builtin_amdgcn_readfirstlane(qb.y);
        int i6 = __builtin_amdgcn_readfirstlane(qb.z);
        int i7 = __builtin_amdgcn_readfirstlane(qb.w);
        ushort_t v0 = hwb[(size_t)i0 * CH + lane];
        ushort_t v1 = hwb[(size_t)i1 * CH + lane];
        ushort_t v2 = hwb[(size_t)i2 * CH + lane];
        ushort_t v3 = hwb[(size_t)i3 * CH + lane];
        ushort_t v4 = hwb[(size_t)i4 * CH + lane];
        ushort_t v5 = hwb[(size_t)i5 * CH + lane];
        ushort_t v6 = hwb[(size_t)i6 * CH + lane];
        ushort_t v7 = hwb[(size_t)i7 * CH + lane];
        a0 += bf2f(v0); a1 += bf2f(v1); a2 += bf2f(v2); a3 += bf2f(v3);
        a4 += bf2f(v4); a5 += bf2f(v5); a6 += bf2f(v6); a7 += bf2f(v7);
    }

    float r = ((a0 + a1) + (a2 + a3)) + ((a4 + a5) + (a6 + a7));
    if (BF16_RELU_OUT) {
        outb[(size_t)node * CH + lane] = f2bf(fmaxf(r, 0.f));
    } else {
        outf[(size_t)node * CH + lane] = r;
    }
}

extern "C" void kernel_launch(void* const* d_in, const int* in_sizes, int n_in,
                              void* d_out, int out_size, void* d_ws, size_t ws_size,
                              hipStream_t stream) {
    const float* x    = (const float*)d_in[0];
    const int*   esrc = (const int*)  d_in[1];
    const int*   edst = (const int*)  d_in[2];
    const float* W1   = (const float*)d_in[3];
    const float* b1   = (const float*)d_in[4];
    const float* W2   = (const float*)d_in[5];
    const float* b2   = (const float*)d_in[6];
    const float* W3   = (const float*)d_in[7];
    const float* b3   = (const float*)d_in[8];
    float* out = (float*)d_out;

    const int N  = in_sizes[0] / 128;
    const int E  = in_sizes[1];
    const int NB = (N + BNODES - 1) / BNODES;   // 782 for N=100000

    // workspace layout (~43 MB)
    char* ws = (char*)d_ws;
    ushort_t* hwb   = (ushort_t*)ws; ws += (size_t)(N + 1) * CH * 2;  // bf16 hw + zero row
    ushort_t* hb    = (ushort_t*)ws; ws += (size_t)N * CH * 2;        // bf16 relu(agg)
    int* bucketed   = (int*)ws;      ws += (size_t)E * 4;
    ws = (char*)(((uintptr_t)ws + 15) & ~(uintptr_t)15);
    int* sorted_src = (int*)ws;      ws += ((size_t)E + (size_t)NB * BSLACK + 64) * 4;
    int2* seg       = (int2*)ws;     ws += (size_t)N * 8;
    int* bcnt       = (int*)ws;      ws += (size_t)NB * 4;
    int* boff       = (int*)ws;      ws += (size_t)(NB + 1) * 4;
    ws = (char*)(((uintptr_t)ws + 63) & ~(uintptr_t)63);
    int* cursor     = (int*)ws;      ws += (size_t)NB * CUR_PAD * 4;
    ws = (char*)(((uintptr_t)ws + 15) & ~(uintptr_t)15);
    ushort_t* Wt1   = (ushort_t*)ws; ws += (size_t)CH * 128 * 2;
    ushort_t* Wt2   = (ushort_t*)ws; ws += (size_t)CH * 64 * 2;
    ushort_t* Wt3   = (ushort_t*)ws; ws += (size_t)CH * 64 * 2;

    dim3 blk(256);
    int gemmGrid = (N + 1 + 127) / 128;          // covers zero row at index N
    int aggGrid  = (N + 3) / 4;
    int scatGrid = (E + SCAT_CHUNK - 1) / SCAT_CHUNK;

    // ---- W transpose+convert (tiny) ----
    wt_kernel<<<1, blk, 0, stream>>>(W1, Wt1, 128);
    wt_kernel<<<1, blk, 0, stream>>>(W2, Wt2, 64);
    wt_kernel<<<1, blk, 0, stream>>>(W3, Wt3, 64);

    // ---- CSR build via buckets (once; shared by all 3 layers) ----
    hipMemsetAsync(bcnt, 0, (size_t)NB * 4, stream);
    bucket_hist<<<256, blk, 0, stream>>>(edst, bcnt, E, NB);
    bucket_scan<<<1, blk, 0, stream>>>(bcnt, boff, cursor, NB);
    bucket_scatter_blk<<<scatGrid, dim3(SCAT_THREADS), 0, stream>>>(esrc, edst, cursor, bucketed, E, NB);
    node_sort<<<NB, blk, 0, stream>>>(bucketed, boff, sorted_src, seg, N, N /*zero row*/);

    // ---- layer 1 ----
    gemm_mfma<128, float><<<gemmGrid, blk, 0, stream>>>(x, Wt1, hwb, N);
    aggregate_kernel<true><<<aggGrid, blk, 0, stream>>>(hwb, sorted_src, seg, b1, hb, nullptr, N);
    // ---- layer 2 ----
    gemm_mfma<64, ushort_t><<<gemmGrid, blk, 0, stream>>>(hb, Wt2, hwb, N);
    aggregate_kernel<true><<<aggGrid, blk, 0, stream>>>(hwb, sorted_src, seg, b2, hb, nullptr, N);
    // ---- layer 3 ----
    gemm_mfma<64, ushort_t><<<gemmGrid, blk, 0, stream>>>(hb, Wt3, hwb, N);
    aggregate_kernel<false><<<aggGrid, blk, 0, stream>>>(hwb, sorted_src, seg, b3, nullptr, out, N);
}